// Round 1
// baseline (129.830 us; speedup 1.0000x reference)
//
#include <hip/hip_runtime.h>
#include <math.h>

#define NFRAMES 16384
#define NJOINTS 22
#define NPATHS  5
#define NPAIRS  (NPATHS * NPATHS)

// PATHS = [[2,5,8,11],[1,4,7,10],[3,6,9,12,15],[14,17,19,21],[13,16,18,20]]
__constant__ int c_pathj[NPATHS][5] = {
    {2, 5, 8, 11, 0},
    {1, 4, 7, 10, 0},
    {3, 6, 9, 12, 15},
    {14, 17, 19, 21, 0},
    {13, 16, 18, 20, 0}
};
__constant__ int c_plen[NPATHS] = {4, 4, 5, 4, 4};

struct F3 { float x, y, z; };

__device__ __forceinline__ F3 f3(float x, float y, float z) { F3 r; r.x = x; r.y = y; r.z = z; return r; }
__device__ __forceinline__ F3 sub3(F3 a, F3 b) { return f3(a.x - b.x, a.y - b.y, a.z - b.z); }
__device__ __forceinline__ float dot3(F3 a, F3 b) { return a.x * b.x + a.y * b.y + a.z * b.z; }
__device__ __forceinline__ F3 cross3(F3 a, F3 b) {
    return f3(a.y * b.z - a.z * b.y,
              a.z * b.x - a.x * b.z,
              a.x * b.y - a.y * b.x);
}
// jnp-style safe normalize: v/||v|| if ||v||>0 else 0
__device__ __forceinline__ F3 safenorm3(F3 v) {
    float n2 = dot3(v, v);
    float n = sqrtf(n2);
    if (n > 0.0f) {
        float r = 1.0f / n;
        return f3(v.x * r, v.y * r, v.z * r);
    }
    return f3(0.0f, 0.0f, 0.0f);
}
__device__ __forceinline__ float clamp1(float d) {
    return fminf(1.0f, fmaxf(-1.0f, d));
}

// Per-frame bbox overlap flag (x and z axes over all joints).
__global__ void k_overlap(const float* __restrict__ m1, const float* __restrict__ m2,
                          int* __restrict__ ov) {
    int f = blockIdx.x * blockDim.x + threadIdx.x;
    if (f >= NFRAMES) return;
    const float* a = m1 + (size_t)f * NJOINTS * 3;
    const float* b = m2 + (size_t)f * NJOINTS * 3;
    float x1n = a[0], x1x = a[0], z1n = a[2], z1x = a[2];
    float x2n = b[0], x2x = b[0], z2n = b[2], z2x = b[2];
#pragma unroll
    for (int j = 1; j < NJOINTS; j++) {
        float ax = a[j * 3 + 0], az = a[j * 3 + 2];
        x1n = fminf(x1n, ax); x1x = fmaxf(x1x, ax);
        z1n = fminf(z1n, az); z1x = fmaxf(z1x, az);
        float bx = b[j * 3 + 0], bz = b[j * 3 + 2];
        x2n = fminf(x2n, bx); x2x = fmaxf(x2x, bx);
        z2n = fminf(z2n, bz); z2x = fmaxf(z2x, bz);
    }
    bool ovx = !((x1x < x2n) || (x2x < x1n));
    bool ovz = !((z1x < z2n) || (z2x < z1n));
    ov[f] = (ovx && ovz) ? 1 : 0;
}

// One thread per (frame, path-pair): sum of GLI over the segment grid.
__global__ void k_gli(const float* __restrict__ m1, const float* __restrict__ m2,
                      float* __restrict__ gli) {
    int idx = blockIdx.x * blockDim.x + threadIdx.x;
    if (idx >= NFRAMES * NPAIRS) return;
    int f = idx / NPAIRS;
    int pr = idx % NPAIRS;
    int pa = pr / NPATHS;
    int pb = pr % NPATHS;
    int la = c_plen[pa];
    int lb = c_plen[pb];

    const float* a = m1 + (size_t)f * NJOINTS * 3;
    const float* b = m2 + (size_t)f * NJOINTS * 3;

    float p1[5][3], p2[5][3];
    for (int i = 0; i < la; i++) {
        int j = c_pathj[pa][i];
        p1[i][0] = a[j * 3 + 0];
        p1[i][1] = a[j * 3 + 1];
        p1[i][2] = a[j * 3 + 2];
    }
    for (int i = 0; i < lb; i++) {
        int j = c_pathj[pb][i];
        p2[i][0] = b[j * 3 + 0];
        p2[i][1] = b[j * 3 + 1];
        p2[i][2] = b[j * 3 + 2];
    }

    float acc = 0.0f;
    for (int i = 0; i + 1 < la; i++) {
        F3 s1 = f3(p1[i][0], p1[i][1], p1[i][2]);
        F3 e1 = f3(p1[i + 1][0], p1[i + 1][1], p1[i + 1][2]);
        F3 r12 = sub3(e1, s1);
        for (int j = 0; j + 1 < lb; j++) {
            F3 s2 = f3(p2[j][0], p2[j][1], p2[j][2]);
            F3 e2 = f3(p2[j + 1][0], p2[j + 1][1], p2[j + 1][2]);
            F3 r13 = sub3(s2, s1);
            F3 r14 = sub3(e2, s1);
            F3 r23 = sub3(s2, e1);
            F3 r24 = sub3(e2, e1);
            F3 r34 = sub3(e2, s2);

            F3 n0 = safenorm3(cross3(r13, r14));
            F3 n1 = safenorm3(cross3(r14, r24));
            F3 n2 = safenorm3(cross3(r24, r23));
            F3 n3 = safenorm3(cross3(r23, r13));

            float g = asinf(clamp1(dot3(n0, n1)))
                    + asinf(clamp1(dot3(n1, n2)))
                    + asinf(clamp1(dot3(n2, n3)))
                    + asinf(clamp1(dot3(n3, n0)));

            float sign = dot3(cross3(r34, r12), r13);
            acc += (sign > 0.0f) ? g : -g;
        }
    }
    gli[idx] = acc * 0.07957747154594767f;  // 1/(4*pi)
}

// out[f] = max_j | gli[f+1][j]*mask[f+1] - gli[f][j]*mask[f] |
// mask[i] = ov[i-1] | ov[i] | ov[i+1]  (out-of-range -> false)
__global__ void k_out(const float* __restrict__ gli, const int* __restrict__ ov,
                      float* __restrict__ out) {
    int f = blockIdx.x * blockDim.x + threadIdx.x;
    if (f >= NFRAMES - 1) return;

    int m0 = ov[f];
    if (f > 0) m0 |= ov[f - 1];
    m0 |= ov[f + 1];  // f+1 <= NFRAMES-1 always here

    int m1 = ov[f + 1] | ov[f];
    if (f + 2 <= NFRAMES - 1) m1 |= ov[f + 2];

    float ma = m0 ? 1.0f : 0.0f;
    float mb = m1 ? 1.0f : 0.0f;

    const float* g0 = gli + (size_t)f * NPAIRS;
    const float* g1 = g0 + NPAIRS;
    float v = 0.0f;
#pragma unroll
    for (int j = 0; j < NPAIRS; j++) {
        v = fmaxf(v, fabsf(g1[j] * mb - g0[j] * ma));
    }
    out[f] = v;
}

extern "C" void kernel_launch(void* const* d_in, const int* in_sizes, int n_in,
                              void* d_out, int out_size, void* d_ws, size_t ws_size,
                              hipStream_t stream) {
    const float* m1 = (const float*)d_in[0];
    const float* m2 = (const float*)d_in[1];
    float* out = (float*)d_out;

    float* gli = (float*)d_ws;                       // NFRAMES*25 floats = 1.6384 MB
    int* ov = (int*)(gli + (size_t)NFRAMES * NPAIRS); // NFRAMES ints = 64 KB

    {
        int threads = 256;
        int blocks = (NFRAMES + threads - 1) / threads;
        k_overlap<<<blocks, threads, 0, stream>>>(m1, m2, ov);
    }
    {
        int total = NFRAMES * NPAIRS;
        int threads = 256;
        int blocks = (total + threads - 1) / threads;
        k_gli<<<blocks, threads, 0, stream>>>(m1, m2, gli);
    }
    {
        int threads = 256;
        int blocks = (NFRAMES - 1 + threads - 1) / threads;
        k_out<<<blocks, threads, 0, stream>>>(gli, ov, out);
    }
}

// Round 2
// 93.415 us; speedup vs baseline: 1.3898x; 1.3898x over previous
//
#include <hip/hip_runtime.h>
#include <math.h>

#define NFRAMES 16384
#define NJOINTS 22
#define NPATHS  5
#define NPAIRS  (NPATHS * NPATHS)
#define NSEG    16   // total segments per motion: 3+3+4+3+3

// Segment tables: seg k spans joints (c_seg_s[k], c_seg_e[k]) and belongs to
// path with range [c_pstart[p], c_pstart[p]+c_plen[p])
__constant__ int c_seg_s[NSEG]  = {2,5,8,  1,4,7,  3,6,9,12,  14,17,19, 13,16,18};
__constant__ int c_seg_e[NSEG]  = {5,8,11, 4,7,10, 6,9,12,15, 17,19,21, 16,18,20};
__constant__ int c_pstart[NPATHS] = {0, 3, 6, 10, 13};
__constant__ int c_plen[NPATHS]   = {3, 3, 4, 3, 3};

struct F3 { float x, y, z; };
__device__ __forceinline__ F3 mk3(float x, float y, float z) { F3 r; r.x=x; r.y=y; r.z=z; return r; }
__device__ __forceinline__ F3 sub3(F3 a, F3 b) { return mk3(a.x-b.x, a.y-b.y, a.z-b.z); }
__device__ __forceinline__ float dot3(F3 a, F3 b) { return a.x*b.x + a.y*b.y + a.z*b.z; }
__device__ __forceinline__ F3 cross3(F3 a, F3 b) {
    return mk3(a.y*b.z - a.z*b.y,
               a.z*b.x - a.x*b.z,
               a.x*b.y - a.y*b.x);
}

// asin via Abramowitz-Stegun 4.4.46: acos(a) = sqrt(1-a)*poly(a), |eps|<=2e-8
// asin(x) = sign(x) * (pi/2 - acos(|x|)),  for |x| <= 1
__device__ __forceinline__ float fast_asin(float x) {
    float a = fabsf(x);
    float p = fmaf(a, -0.0012624911f,  0.0066700901f);
    p = fmaf(a, p, -0.0170881256f);
    p = fmaf(a, p,  0.0308918810f);
    p = fmaf(a, p, -0.0501743046f);
    p = fmaf(a, p,  0.0889789874f);
    p = fmaf(a, p, -0.2145988016f);
    p = fmaf(a, p,  1.5707963050f);
    float r = 1.5707963268f - sqrtf(1.0f - a) * p;
    return copysignf(r, x);
}

// asin(clamp(dot(f_i,f_j)/(|f_i||f_j|))) with jnp safe-normalize semantics
// (zero-norm face -> normalized vec 0 -> dot 0 -> asin 0)
__device__ __forceinline__ float asin_term(float d, float ma, float mb) {
    float rs = __frsqrt_rn(ma * mb);
    float x = fminf(1.0f, fmaxf(-1.0f, d * rs));
    float r = fast_asin(x);
    return (ma > 0.0f && mb > 0.0f) ? r : 0.0f;
}

// One block (256 threads) per frame. Thread t computes the GLI term for
// segment pair (i = t>>4 in motion1, j = t&15 in motion2), LDS-reduce into
// the 25 path-pair bins. Lane 64 computes the bbox-overlap flag.
__global__ __launch_bounds__(256) void k_gli(const float* __restrict__ m1,
                                             const float* __restrict__ m2,
                                             float* __restrict__ gli,
                                             int* __restrict__ ov) {
    __shared__ float sA[NJOINTS * 3];
    __shared__ float sB[NJOINTS * 3];
    __shared__ float sT[256];

    int f = blockIdx.x;
    int t = threadIdx.x;
    const float* a = m1 + (size_t)f * NJOINTS * 3;
    const float* b = m2 + (size_t)f * NJOINTS * 3;
    if (t < NJOINTS * 3) { sA[t] = a[t]; sB[t] = b[t]; }
    __syncthreads();

    int i = t >> 4;
    int j = t & 15;
    int s1o = c_seg_s[i] * 3, e1o = c_seg_e[i] * 3;
    int s2o = c_seg_s[j] * 3, e2o = c_seg_e[j] * 3;
    F3 s1 = mk3(sA[s1o], sA[s1o+1], sA[s1o+2]);
    F3 e1 = mk3(sA[e1o], sA[e1o+1], sA[e1o+2]);
    F3 s2 = mk3(sB[s2o], sB[s2o+1], sB[s2o+2]);
    F3 e2 = mk3(sB[e2o], sB[e2o+1], sB[e2o+2]);

    F3 r13 = sub3(s2, s1);
    F3 r14 = sub3(e2, s1);
    F3 r23 = sub3(s2, e1);
    F3 r24 = sub3(e2, e1);
    F3 r12 = sub3(e1, s1);
    F3 r34 = sub3(e2, s2);

    F3 f0 = cross3(r13, r14);
    F3 f1 = cross3(r14, r24);
    F3 f2 = cross3(r24, r23);
    F3 f3 = cross3(r23, r13);
    float m0 = dot3(f0, f0);
    float n1 = dot3(f1, f1);
    float n2 = dot3(f2, f2);
    float m3 = dot3(f3, f3);

    float g = asin_term(dot3(f0, f1), m0, n1)
            + asin_term(dot3(f1, f2), n1, n2)
            + asin_term(dot3(f2, f3), n2, m3)
            + asin_term(dot3(f3, f0), m3, m0);

    float sg = dot3(cross3(r34, r12), r13);
    sT[t] = (sg > 0.0f) ? g : -g;
    __syncthreads();

    if (t < NPAIRS) {
        int pa = t / NPATHS;
        int pb = t % NPATHS;
        int ia0 = c_pstart[pa], na = c_plen[pa];
        int ib0 = c_pstart[pb], nb = c_plen[pb];
        float s = 0.0f;
        for (int ia = ia0; ia < ia0 + na; ia++)
            for (int ib = ib0; ib < ib0 + nb; ib++)
                s += sT[ia * 16 + ib];
        gli[(size_t)f * NPAIRS + t] = s * 0.07957747154594767f;  // 1/(4*pi)
    } else if (t == 64) {
        float x1n = sA[0], x1x = sA[0], z1n = sA[2], z1x = sA[2];
        float x2n = sB[0], x2x = sB[0], z2n = sB[2], z2x = sB[2];
#pragma unroll
        for (int jj = 1; jj < NJOINTS; jj++) {
            float ax = sA[jj*3+0], az = sA[jj*3+2];
            x1n = fminf(x1n, ax); x1x = fmaxf(x1x, ax);
            z1n = fminf(z1n, az); z1x = fmaxf(z1x, az);
            float bx = sB[jj*3+0], bz = sB[jj*3+2];
            x2n = fminf(x2n, bx); x2x = fmaxf(x2x, bx);
            z2n = fminf(z2n, bz); z2x = fmaxf(z2x, bz);
        }
        bool ovx = !((x1x < x2n) || (x2x < x1n));
        bool ovz = !((z1x < z2n) || (z2x < z1n));
        ov[f] = (ovx && ovz) ? 1 : 0;
    }
}

// out[f] = max_j | gli[f+1][j]*mask[f+1] - gli[f][j]*mask[f] |
// mask[i] = ov[i-1] | ov[i] | ov[i+1]  (out-of-range -> false)
__global__ void k_out(const float* __restrict__ gli, const int* __restrict__ ov,
                      float* __restrict__ out) {
    int f = blockIdx.x * blockDim.x + threadIdx.x;
    if (f >= NFRAMES - 1) return;

    int m0 = ov[f];
    if (f > 0) m0 |= ov[f - 1];
    m0 |= ov[f + 1];

    int m1 = ov[f + 1] | ov[f];
    if (f + 2 <= NFRAMES - 1) m1 |= ov[f + 2];

    float ma = m0 ? 1.0f : 0.0f;
    float mb = m1 ? 1.0f : 0.0f;

    const float* g0 = gli + (size_t)f * NPAIRS;
    const float* g1 = g0 + NPAIRS;
    float v = 0.0f;
#pragma unroll
    for (int j = 0; j < NPAIRS; j++) {
        v = fmaxf(v, fabsf(g1[j] * mb - g0[j] * ma));
    }
    out[f] = v;
}

extern "C" void kernel_launch(void* const* d_in, const int* in_sizes, int n_in,
                              void* d_out, int out_size, void* d_ws, size_t ws_size,
                              hipStream_t stream) {
    const float* m1 = (const float*)d_in[0];
    const float* m2 = (const float*)d_in[1];
    float* out = (float*)d_out;

    float* gli = (float*)d_ws;                        // NFRAMES*25 floats
    int* ov = (int*)(gli + (size_t)NFRAMES * NPAIRS); // NFRAMES ints

    k_gli<<<NFRAMES, 256, 0, stream>>>(m1, m2, gli, ov);

    {
        int threads = 256;
        int blocks = (NFRAMES - 1 + threads - 1) / threads;
        k_out<<<blocks, threads, 0, stream>>>(gli, ov, out);
    }
}

// Round 3
// 85.574 us; speedup vs baseline: 1.5172x; 1.0916x over previous
//
#include <hip/hip_runtime.h>
#include <math.h>

#define NFRAMES 16384
#define NJOINTS 22
#define NPATHS  5
#define NPAIRS  (NPATHS * NPATHS)
#define NSEG    16   // total segments per motion: 3+3+4+3+3

// Segment k spans joints (c_seg_s[k], c_seg_e[k]); path p owns segment
// range [c_pstart[p], c_pstart[p]+c_plen[p]).
__constant__ int c_seg_s[NSEG]  = {2,5,8,  1,4,7,  3,6,9,12,  14,17,19, 13,16,18};
__constant__ int c_seg_e[NSEG]  = {5,8,11, 4,7,10, 6,9,12,15, 17,19,21, 16,18,20};
__constant__ int c_pstart[NPATHS] = {0, 3, 6, 10, 13};
__constant__ int c_plen[NPATHS]   = {3, 3, 4, 3, 3};

struct F3 { float x, y, z; };
__device__ __forceinline__ F3 mk3(float x, float y, float z) { F3 r; r.x=x; r.y=y; r.z=z; return r; }
__device__ __forceinline__ F3 sub3(F3 a, F3 b) { return mk3(a.x-b.x, a.y-b.y, a.z-b.z); }
__device__ __forceinline__ float dot3(F3 a, F3 b) { return a.x*b.x + a.y*b.y + a.z*b.z; }
__device__ __forceinline__ F3 cross3(F3 a, F3 b) {
    return mk3(a.y*b.z - a.z*b.y,
               a.z*b.x - a.x*b.z,
               a.x*b.y - a.y*b.x);
}

// asin via A&S 4.4.46: acos(a) = sqrt(1-a)*poly(a), |eps|<=2e-8
// asin(x) = sign(x) * (pi/2 - acos(|x|)), |x| <= 1
__device__ __forceinline__ float fast_asin(float x) {
    float a = fabsf(x);
    float p = fmaf(a, -0.0012624911f,  0.0066700901f);
    p = fmaf(a, p, -0.0170881256f);
    p = fmaf(a, p,  0.0308918810f);
    p = fmaf(a, p, -0.0501743046f);
    p = fmaf(a, p,  0.0889789874f);
    p = fmaf(a, p, -0.2145988016f);
    p = fmaf(a, p,  1.5707963050f);
    float r = 1.5707963268f - __builtin_amdgcn_sqrtf(1.0f - a) * p;
    return copysignf(r, x);
}

// asin(clamp(d / sqrt(ma*mb))) with jnp safe-normalize semantics
// (zero-norm face -> normalized vec = 0 -> dot 0 -> asin 0)
__device__ __forceinline__ float asin_term(float d, float ma, float mb) {
    float rs = __builtin_amdgcn_rsqf(ma * mb);
    float x = fminf(1.0f, fmaxf(-1.0f, d * rs));
    float r = fast_asin(x);
    return (ma > 0.0f && mb > 0.0f) ? r : 0.0f;
}

// One block (256 threads) per frame. Thread t computes the GLI term for
// segment pair (i = t>>4 of motion1, j = t&15 of motion2); 25 threads then
// bin-reduce via a fully unrolled, padded 16-read LDS gather. Thread 64
// computes the bbox-overlap flag.
__global__ __launch_bounds__(256) void k_gli(const float* __restrict__ m1,
                                             const float* __restrict__ m2,
                                             float* __restrict__ gli,
                                             int* __restrict__ ov) {
    __shared__ float sA[NJOINTS * 3];
    __shared__ float sB[NJOINTS * 3];
    __shared__ float sT[257];   // sT[256] = 0.0 pad slot

    int f = blockIdx.x;
    int t = threadIdx.x;
    const float* a = m1 + (size_t)f * NJOINTS * 3;
    const float* b = m2 + (size_t)f * NJOINTS * 3;
    if (t < NJOINTS * 3) { sA[t] = a[t]; sB[t] = b[t]; }
    __syncthreads();

    int i = t >> 4;
    int j = t & 15;
    int s1o = c_seg_s[i] * 3, e1o = c_seg_e[i] * 3;
    int s2o = c_seg_s[j] * 3, e2o = c_seg_e[j] * 3;
    F3 s1 = mk3(sA[s1o], sA[s1o+1], sA[s1o+2]);
    F3 e1 = mk3(sA[e1o], sA[e1o+1], sA[e1o+2]);
    F3 s2 = mk3(sB[s2o], sB[s2o+1], sB[s2o+2]);
    F3 e2 = mk3(sB[e2o], sB[e2o+1], sB[e2o+2]);

    F3 r12 = sub3(e1, s1);
    F3 r13 = sub3(s2, s1);
    F3 r14 = sub3(e2, s1);

    // Faces via 3 crosses:
    //   f0 = r13 x r14, c1 = r12 x r13, c2 = r12 x r14
    //   f1 = c2, f2 = c2 - c1 - f0, f3 = -c1
    //   sign = dot(cross(r34, r12), r13) = -dot(c2, r13)
    F3 f0 = cross3(r13, r14);
    F3 c1 = cross3(r12, r13);
    F3 c2 = cross3(r12, r14);
    F3 f2 = sub3(sub3(c2, c1), f0);

    float q0 = dot3(f0, f0);
    float q1 = dot3(c2, c2);
    float q2 = dot3(f2, f2);
    float q3 = dot3(c1, c1);

    float g = asin_term( dot3(f0, c2), q0, q1)
            + asin_term( dot3(c2, f2), q1, q2)
            + asin_term(-dot3(f2, c1), q2, q3)
            + asin_term(-dot3(c1, f0), q3, q0);

    float sg = -dot3(c2, r13);
    sT[t] = (sg > 0.0f) ? g : -g;
    if (t == 0) sT[256] = 0.0f;
    __syncthreads();

    if (t < NPAIRS) {
        int pa = (t * 205) >> 10;   // t/5 for t<25
        int pb = t - pa * 5;        // t%5
        int ia0 = c_pstart[pa], na = c_plen[pa];
        int ib0 = c_pstart[pb], nb = c_plen[pb];
        float s = 0.0f;
#pragma unroll
        for (int ka = 0; ka < 4; ka++) {
#pragma unroll
            for (int kb = 0; kb < 4; kb++) {
                int idx = (ka < na && kb < nb) ? ((ia0 + ka) * 16 + (ib0 + kb)) : 256;
                s += sT[idx];
            }
        }
        gli[(size_t)f * NPAIRS + t] = s * 0.07957747154594767f;  // 1/(4*pi)
    } else if (t == 64) {
        float x1n = sA[0], x1x = sA[0], z1n = sA[2], z1x = sA[2];
        float x2n = sB[0], x2x = sB[0], z2n = sB[2], z2x = sB[2];
#pragma unroll
        for (int jj = 1; jj < NJOINTS; jj++) {
            float ax = sA[jj*3+0], az = sA[jj*3+2];
            x1n = fminf(x1n, ax); x1x = fmaxf(x1x, ax);
            z1n = fminf(z1n, az); z1x = fmaxf(z1x, az);
            float bx = sB[jj*3+0], bz = sB[jj*3+2];
            x2n = fminf(x2n, bx); x2x = fmaxf(x2x, bx);
            z2n = fminf(z2n, bz); z2x = fmaxf(z2x, bz);
        }
        bool ovx = !((x1x < x2n) || (x2x < x1n));
        bool ovz = !((z1x < z2n) || (z2x < z1n));
        ov[f] = (ovx && ovz) ? 1 : 0;
    }
}

// out[f] = max_j | gli[f+1][j]*mask[f+1] - gli[f][j]*mask[f] |
// mask[i] = ov[i-1] | ov[i] | ov[i+1]  (out-of-range -> false)
__global__ void k_out(const float* __restrict__ gli, const int* __restrict__ ov,
                      float* __restrict__ out) {
    int f = blockIdx.x * blockDim.x + threadIdx.x;
    if (f >= NFRAMES - 1) return;

    int m0 = ov[f];
    if (f > 0) m0 |= ov[f - 1];
    m0 |= ov[f + 1];

    int m1 = ov[f + 1] | ov[f];
    if (f + 2 <= NFRAMES - 1) m1 |= ov[f + 2];

    float ma = m0 ? 1.0f : 0.0f;
    float mb = m1 ? 1.0f : 0.0f;

    const float* g0 = gli + (size_t)f * NPAIRS;
    const float* g1 = g0 + NPAIRS;
    float v = 0.0f;
#pragma unroll
    for (int jj = 0; jj < NPAIRS; jj++) {
        v = fmaxf(v, fabsf(g1[jj] * mb - g0[jj] * ma));
    }
    out[f] = v;
}

extern "C" void kernel_launch(void* const* d_in, const int* in_sizes, int n_in,
                              void* d_out, int out_size, void* d_ws, size_t ws_size,
                              hipStream_t stream) {
    const float* m1 = (const float*)d_in[0];
    const float* m2 = (const float*)d_in[1];
    float* out = (float*)d_out;

    float* gli = (float*)d_ws;                        // NFRAMES*25 floats
    int* ov = (int*)(gli + (size_t)NFRAMES * NPAIRS); // NFRAMES ints

    k_gli<<<NFRAMES, 256, 0, stream>>>(m1, m2, gli, ov);

    {
        int threads = 256;
        int blocks = (NFRAMES - 1 + threads - 1) / threads;
        k_out<<<blocks, threads, 0, stream>>>(gli, ov, out);
    }
}